// Round 14
// baseline (138.909 us; speedup 1.0000x reference)
//
#include <hip/hip_runtime.h>

// CharGRU2: 2-layer GRU (reset_after=true) + dense + softmax, fp32.
// B=2048, T=128, V=256, H=20, L=15.
//
// Round 14: TWO BATCHES PER WAVE on the R11/R12 trunk.
//
// Evidence: R13 (readlane, no LDS) regressed -> broadcast ds_read_b128 is
// cheap; R11/R12's ~420 cyc/SIMD-step stall is DEPENDENT-CHAIN latency
// (dot->sigm->DPP->tanh->update ~150 cyc serial) that 2 waves/SIMD can't
// fill. More waves are impossible (1 batch = 60 lanes, B=2048), so raise
// per-wave ILP instead: each wave runs 2 independent batches. The weight
// VGPRs depend only on the lane's gate column -> SHARED by both batches
// (zero duplication); only state+staging duplicate (~95 regs). Each
// iteration now has 4 independent streams (2 batches x 2 pipelined layers).
// 1024 waves = 1 wave/SIMD on all 256 CUs; waves_per_eu(1,1) -> 512-reg
// budget, ~180 live fits.
//
// Layout recap (per batch, unchanged): lane 16r+3u+p owns gate column
// p*20+(5r+u) (p=0:z 1:r 2:h~); gate hops = 2 chained v_mov_dpp row_shr:1;
// h staged in per-wave LDS, read back as 5x ds_read_b128 wave-uniform
// broadcast; register-staged (R12 style) right after each h-store so the
// single wave never waits on lgkmcnt at the loop top. Cross-layer pipeline:
// iteration i computes L0(t=i) and L1(t=i-1) for both batches.

#define BB 2048
#define TT 128
#define HH 20
#define LL 15
#define H3 60

typedef float v2f __attribute__((ext_vector_type(2)));

__device__ __forceinline__ float bclane(float v, int k) {
    return __int_as_float(__builtin_amdgcn_readlane(__float_as_int(v), k));
}
__device__ __forceinline__ float dpp_rshr1(float v) {
    return __int_as_float(__builtin_amdgcn_update_dpp(
        0, __float_as_int(v), 0x111, 0xF, 0xF, true));
}
__device__ __forceinline__ float fast_rcp(float x) { return __builtin_amdgcn_rcpf(x); }
__device__ __forceinline__ float sigm(float x) { return fast_rcp(1.f + __expf(-x)); }
__device__ __forceinline__ float tanh_f(float x) { return 1.f - 2.f * fast_rcp(1.f + __expf(2.f * x)); }
#define PIN(v) asm volatile("" : "+v"(v))
#define LDSFENCE() asm volatile("" ::: "memory")

extern "C" __global__ __launch_bounds__(256)
__attribute__((amdgpu_waves_per_eu(1, 1)))
void gru2_kernel(const int* __restrict__ x, const float* __restrict__ W0,
                 const float* __restrict__ U0, const float* __restrict__ b0i,
                 const float* __restrict__ b0r, const float* __restrict__ W1,
                 const float* __restrict__ U1, const float* __restrict__ b1i,
                 const float* __restrict__ b1r, const float* __restrict__ Wd,
                 const float* __restrict__ bd, float* __restrict__ out)
{
    const int lane = threadIdx.x & 63;
    const int w = threadIdx.x >> 6;
    const int bA = blockIdx.x * 8 + w * 2;               // two batches per wave
    const int bB = bA + 1;
    const int pos = lane & 15;
    const int pc  = (pos < 15) ? pos : 14;               // lane 16r+15 dups pos 14
    const int u   = pc / 3;
    const int p3  = pc % 3;                              // 0:z 1:r 2:h~
    const int j   = (lane >> 4) * 5 + u;                 // unit 0..19
    const bool home = (pos < 15) && (p3 == 2);
    const int col = p3 * 20 + j;

    // per-wave LDS: [wave][batch][layer][24]
    __shared__ __align__(16) float hbuf[4][2][2][24];
    float* h0A = &hbuf[w][0][0][0];  float* h1A = &hbuf[w][0][1][0];
    float* h0B = &hbuf[w][1][0][0];  float* h1B = &hbuf[w][1][1][0];
    const float4* h0Aq = (const float4*)h0A;  const float4* h1Aq = (const float4*)h1A;
    const float4* h0Bq = (const float4*)h0B;  const float4* h1Bq = (const float4*)h1B;
    if (home) { h0A[j] = 0.f; h1A[j] = 0.f; h0B[j] = 0.f; h1B[j] = 0.f; }
    LDSFENCE();

    // ---- weight columns (k-pair packed), SHARED by both batches ----
    v2f u0p[10], w1p[10], u1p[10];
#pragma unroll
    for (int q = 0; q < 10; ++q) {
        const int k0 = (2 * q) * H3, k1 = (2 * q + 1) * H3;
        u0p[q] = v2f{U0[k0 + col], U0[k1 + col]};
        w1p[q] = v2f{W1[k0 + col], W1[k1 + col]};
        u1p[q] = v2f{U1[k0 + col], U1[k1 + col]};
    }
#pragma unroll
    for (int q = 0; q < 10; ++q) { PIN(u0p[q]); PIN(w1p[q]); PIN(u1p[q]); }
    float bi0 = b0i[col], br0 = b0r[col], bi1 = b1i[col], br1 = b1r[col];
    PIN(bi0); PIN(br0); PIN(bi1); PIN(br1);

    // ---- tokens for both batches ----
    const int* xrA = x + bA * TT;
    const int* xrB = x + bB * TT;
    const int tA0 = xrA[lane], tA1 = xrA[64 + lane];
    const int tB0 = xrB[lane], tB1 = xrB[64 + lane];

    float h0a = 0.f, h1a = 0.f, h0b = 0.f, h1b = 0.f;
    float4 c0a[5], c1a[5], c0b[5], c1b[5];               // register-staged h quads

    auto dot = [&](const float4* c, const v2f* wp, float bias) -> float {
        v2f s0 = v2f{bias, 0.f}, s1 = v2f{0.f, 0.f};
#pragma unroll
        for (int q = 0; q < 5; ++q) {
            s0 = __builtin_elementwise_fma(v2f{c[q].x, c[q].y}, wp[2 * q], s0);
            s1 = __builtin_elementwise_fma(v2f{c[q].z, c[q].w}, wp[2 * q + 1], s1);
        }
        return (s0.x + s0.y) + (s1.x + s1.y);
    };
    auto gates = [&](float xw, float rec, float& h) {
        const float sg = sigm(xw + rec);
        const float rv = dpp_rshr1(sg);
        const float zv = dpp_rshr1(rv);
        const float hh = tanh_f(xw + rv * rec);
        h = fmaf(zv, h - hh, hh);
    };

    // ---- W0 pipelines ----
    int tka2 = __builtin_amdgcn_readlane(tA0, 2);
    int tkb2 = __builtin_amdgcn_readlane(tB0, 2);
    float xwa = W0[__builtin_amdgcn_readlane(tA0, 0) * H3 + col] + bi0;
    float xwa_n = W0[__builtin_amdgcn_readlane(tA0, 1) * H3 + col];
    float xwb = W0[__builtin_amdgcn_readlane(tB0, 0) * H3 + col] + bi0;
    float xwb_n = W0[__builtin_amdgcn_readlane(tB0, 1) * H3 + col];

    // ---- prologue: L0 t=0 for both batches ----
    {
        const float pfa = W0[tka2 * H3 + col];
        const float pfb = W0[tkb2 * H3 + col];
        gates(xwa, br0, h0a);
        gates(xwb, br0, h0b);
        if (home) { h0A[j] = h0a; h0B[j] = h0b; }
        LDSFENCE();
#pragma unroll
        for (int q = 0; q < 5; ++q) {
            c0a[q] = h0Aq[q]; c0b[q] = h0Bq[q];
            c1a[q] = h1Aq[q]; c1b[q] = h1Bq[q];
        }
        xwa = xwa_n + bi0; xwa_n = pfa; tka2 = __builtin_amdgcn_readlane(tA0, 3);
        xwb = xwb_n + bi0; xwb_n = pfb; tkb2 = __builtin_amdgcn_readlane(tB0, 3);
    }

    // ---- main loop: i = 1..127 ----
    for (int i = 1; i < TT; ++i) {
        const int t3 = (i + 3 < TT) ? (i + 3) : (TT - 1);
        const float pfa = W0[tka2 * H3 + col];
        const float pfb = W0[tkb2 * H3 + col];
        const int tka3 = __builtin_amdgcn_readlane(t3 < 64 ? tA0 : tA1, t3 & 63);
        const int tkb3 = __builtin_amdgcn_readlane(t3 < 64 ? tB0 : tB1, t3 & 63);

        // six dots (3 per batch), all from registers, mutually independent
        const float rec0a = dot(c0a, u0p, br0);
        const float rec0b = dot(c0b, u0p, br0);
        const float xw1a  = dot(c0a, w1p, bi1);
        const float xw1b  = dot(c0b, w1p, bi1);
        const float rec1a = dot(c1a, u1p, br1);
        const float rec1b = dot(c1b, u1p, br1);

        // L0 gates (t=i), both batches (independent)
        gates(xwa, rec0a, h0a);
        gates(xwb, rec0b, h0b);
        if (home) { h0A[j] = h0a; h0B[j] = h0b; }
        LDSFENCE();
#pragma unroll
        for (int q = 0; q < 5; ++q) { c0a[q] = h0Aq[q]; c0b[q] = h0Bq[q]; }

        // L1 gates (t=i-1), both batches (independent of L0 above)
        gates(xw1a, rec1a, h1a);
        gates(xw1b, rec1b, h1b);
        if (home) { h1A[j] = h1a; h1B[j] = h1b; }
        LDSFENCE();
#pragma unroll
        for (int q = 0; q < 5; ++q) { c1a[q] = h1Aq[q]; c1b[q] = h1Bq[q]; }

        // rotate W0 pipelines
        xwa = xwa_n + bi0; xwa_n = pfa; tka2 = tka3;
        xwb = xwb_n + bi0; xwb_n = pfb; tkb2 = tkb3;
    }

    // ---- epilogue: L1 t=127 for both batches ----
    {
        const float xw1a  = dot(c0a, w1p, bi1);
        const float xw1b  = dot(c0b, w1p, bi1);
        const float rec1a = dot(c1a, u1p, br1);
        const float rec1b = dot(c1b, u1p, br1);
        gates(xw1a, rec1a, h1a);
        gates(xw1b, rec1b, h1b);
        if (home) { h1A[j] = h1a; h1B[j] = h1b; }
        LDSFENCE();
    }

    // ---- dense (h1 @ Wd + bd) + softmax for both batches, lanes 0..14 ----
    const int l = lane < LL ? lane : LL - 1;
    float accA = bd[l], accB = accA;
#pragma unroll
    for (int k = 0; k < HH; ++k) {
        const float wd = Wd[k * LL + l];
        accA = fmaf(h1A[k], wd, accA);                   // LDS broadcast reads
        accB = fmaf(h1B[k], wd, accB);
    }
    float mA = accA, mB = accB;
#pragma unroll
    for (int i = 0; i < LL; ++i) {
        mA = fmaxf(mA, bclane(accA, i));
        mB = fmaxf(mB, bclane(accB, i));
    }
    const float eA = __expf(accA - mA);
    const float eB = __expf(accB - mB);
    float sA = 0.f, sB = 0.f;
#pragma unroll
    for (int i = 0; i < LL; ++i) {
        sA += bclane(eA, i);
        sB += bclane(eB, i);
    }
    if (lane < LL) {
        out[bA * LL + lane] = eA * fast_rcp(sA);
        out[bB * LL + lane] = eB * fast_rcp(sB);
    }
}

extern "C" void kernel_launch(void* const* d_in, const int* in_sizes, int n_in,
                              void* d_out, int out_size, void* d_ws, size_t ws_size,
                              hipStream_t stream) {
    const int*   x   = (const int*)  d_in[0];
    const float* W0  = (const float*)d_in[1];
    const float* U0  = (const float*)d_in[2];
    const float* b0i = (const float*)d_in[3];
    const float* b0r = (const float*)d_in[4];
    const float* W1  = (const float*)d_in[5];
    const float* U1  = (const float*)d_in[6];
    const float* b1i = (const float*)d_in[7];
    const float* b1r = (const float*)d_in[8];
    const float* Wd  = (const float*)d_in[9];
    const float* bd  = (const float*)d_in[10];
    // d_in[11] = drop_rate (identity), unused
    float* out = (float*)d_out;

    // 2 batches/wave, 4 waves/block -> 256 blocks = 1 block/CU = 1 wave/SIMD.
    dim3 grid(BB / 8), block(256);
    hipLaunchKernelGGL(gru2_kernel, grid, block, 0, stream,
                       x, W0, U0, b0i, b0r, W1, U1, b1i, b1r, Wd, bd, out);
}